// Round 1
// baseline (15594.716 us; speedup 1.0000x reference)
//
#include <hip/hip_runtime.h>

typedef unsigned short u16;
typedef unsigned int u32;
typedef unsigned long long u64;
typedef __attribute__((ext_vector_type(8))) short bf16x8;
typedef __attribute__((ext_vector_type(4))) float f32x4;
typedef __attribute__((ext_vector_type(8))) unsigned short u16x8;
typedef __attribute__((ext_vector_type(4))) unsigned short u16x4;

#define MFMA16(a, b, c) __builtin_amdgcn_mfma_f32_16x16x32_bf16(a, b, c, 0, 0, 0)

__device__ __forceinline__ u16 f2b(float f) {
    u32 u = __builtin_bit_cast(u32, f);
    u32 r = (u + 0x7fffu + ((u >> 16) & 1u)) >> 16;
    return (u16)r;
}
__device__ __forceinline__ float b2f(u16 h) {
    u32 u = ((u32)h) << 16;
    return __builtin_bit_cast(float, u);
}
__device__ __forceinline__ float sigm(float x) { return 1.0f / (1.0f + __expf(-x)); }
__device__ __forceinline__ float tanh_fast(float x) { return 1.0f - 2.0f / (__expf(2.0f * x) + 1.0f); }

// ---------------------------------------------------------------------------
// Embedding gather + f32->bf16 cast, time-major output x[t*64+b][e]
__global__ __launch_bounds__(256) void embed_k(const int* __restrict__ enc,
                                               const float* __restrict__ emb,
                                               u16* __restrict__ xb) {
    int idx = (blockIdx.x * 256 + threadIdx.x) * 4;  // element index into [16384][512]
    int row = idx >> 9;
    int e = idx & 511;
    int t = row >> 6, b = row & 63;
    int tok = enc[b * 256 + t];
    const float4 v = *(const float4*)(emb + (size_t)tok * 512 + e);
    u16x4 o;
    o.x = f2b(v.x); o.y = f2b(v.y); o.z = f2b(v.z); o.w = f2b(v.w);
    *(u16x4*)(xb + idx) = o;
}

// Mask words: maskw[t] bit b = (enc[b][t] != 0)
__global__ void mask_k(const int* __restrict__ enc, u64* __restrict__ mw) {
    int t = threadIdx.x;  // 256 threads
    u64 m = 0;
#pragma unroll 8
    for (int b = 0; b < 64; ++b)
        if (enc[b * 256 + t] != 0) m |= (1ull << b);
    mw[t] = m;
}

// ---------------------------------------------------------------------------
// Cast f32 [K][N] -> bf16 transposed [N][K] via LDS tile
__global__ __launch_bounds__(256) void castT_k(const float* __restrict__ src,
                                               u16* __restrict__ dst, int K, int N) {
    __shared__ float tile[64][65];
    int n0 = blockIdx.x * 64, k0 = blockIdx.y * 64;
    int tid = threadIdx.x;
#pragma unroll
    for (int it = 0; it < 4; ++it) {
        int e = tid + it * 256;      // 0..1023 float4 units
        int kk = e >> 4;             // 0..63
        int nn = (e & 15) * 4;       // 0..60
        const float4 v = *(const float4*)(src + (size_t)(k0 + kk) * N + n0 + nn);
        tile[kk][nn] = v.x; tile[kk][nn + 1] = v.y;
        tile[kk][nn + 2] = v.z; tile[kk][nn + 3] = v.w;
    }
    __syncthreads();
#pragma unroll
    for (int it = 0; it < 2; ++it) {
        int e = tid + it * 256;      // 0..511
        int nn = e >> 3;             // 0..63
        int ks = (e & 7) * 8;        // 0..56
        u16x8 o;
#pragma unroll
        for (int j = 0; j < 8; ++j) o[j] = f2b(tile[ks + j][nn]);
        *(u16x8*)(dst + (size_t)(n0 + nn) * K + k0 + ks) = o;
    }
}

// ---------------------------------------------------------------------------
// bf16 MFMA GEMM: out[dir] = A[16384][Ak] @ Bt[dir]^T + bias[dir]; Bt is [2048][Ak].
// 128x128 tile per WG, 4 waves each 64x64 (4x4 of 16x16x32 MFMA), BK=32.
__global__ __launch_bounds__(256) void gemm_bias_k(
    const u16* __restrict__ A, int Ak,
    const u16* __restrict__ BtF, const u16* __restrict__ BtB,
    const float* __restrict__ biasF, const float* __restrict__ biasB,
    u16* __restrict__ outF, u16* __restrict__ outB) {
    const int dir = blockIdx.z;
    const u16* __restrict__ Bt = dir ? BtB : BtF;
    const float* __restrict__ bias = dir ? biasB : biasF;
    u16* __restrict__ out = dir ? outB : outF;

    const int m0 = blockIdx.y * 128, n0 = blockIdx.x * 128;
    __shared__ __align__(16) u16 As[128 * 40];
    __shared__ __align__(16) u16 Bs[128 * 40];
    const int tid = threadIdx.x;
    const int lane = tid & 63, w = tid >> 6;
    const int l15 = lane & 15, quad = lane >> 4;
    const int rb = (w >> 1) * 64, cb = (w & 1) * 64;

    f32x4 acc[4][4];
#pragma unroll
    for (int i = 0; i < 4; ++i)
#pragma unroll
        for (int j = 0; j < 4; ++j) acc[i][j] = (f32x4){0.f, 0.f, 0.f, 0.f};

    const int nkt = Ak >> 5;
    for (int kt = 0; kt < nkt; ++kt) {
        __syncthreads();
#pragma unroll
        for (int it = 0; it < 2; ++it) {
            int s = tid + it * 256;
            int r = s >> 2, seg = s & 3;
            *(uint4*)&As[r * 40 + seg * 8] =
                *(const uint4*)&A[(size_t)(m0 + r) * Ak + kt * 32 + seg * 8];
            *(uint4*)&Bs[r * 40 + seg * 8] =
                *(const uint4*)&Bt[(size_t)(n0 + r) * Ak + kt * 32 + seg * 8];
        }
        __syncthreads();
        bf16x8 af[4], bfr[4];
#pragma unroll
        for (int i = 0; i < 4; ++i)
            af[i] = *(const bf16x8*)&As[(rb + i * 16 + l15) * 40 + quad * 8];
#pragma unroll
        for (int j = 0; j < 4; ++j)
            bfr[j] = *(const bf16x8*)&Bs[(cb + j * 16 + l15) * 40 + quad * 8];
#pragma unroll
        for (int i = 0; i < 4; ++i)
#pragma unroll
            for (int j = 0; j < 4; ++j) acc[i][j] = MFMA16(af[i], bfr[j], acc[i][j]);
    }
    // epilogue: add bias, store bf16
#pragma unroll
    for (int j = 0; j < 4; ++j) {
        int col = n0 + cb + j * 16 + l15;
        float bv = bias[col];
#pragma unroll
        for (int i = 0; i < 4; ++i) {
#pragma unroll
            for (int r = 0; r < 4; ++r) {
                int row = m0 + rb + i * 16 + quad * 4 + r;
                out[(size_t)row * 2048 + col] = f2b(acc[i][j][r] + bv);
            }
        }
    }
}

// ---------------------------------------------------------------------------
// Persistent bidirectional LSTM recurrence.
// grid = 128 WGs: WG 0..63 forward, 64..127 backward. Each WG owns 8 units
// (32 gate-cols) whose U-slices live in registers. Per step: z = zx[t] + h@U,
// gates, masked update, write h slice to double-buffered global h, spin-barrier.
__global__ __launch_bounds__(256, 1) void lstm_rec_k(
    const u16* __restrict__ zxF, const u16* __restrict__ zxB,  // [256*64][2048]
    const u16* __restrict__ UtF, const u16* __restrict__ UtB,  // [2048][512]
    const u64* __restrict__ maskw,
    u16* __restrict__ hbufF, u16* __restrict__ hbufB,          // each 2*[64*512]
    u32* __restrict__ ctrF, u32* __restrict__ ctrB,
    u16* __restrict__ out1,    // layer 1: [256][64][1024] bf16
    float* __restrict__ out2,  // layer 2: d_out
    int layer) {
    const int wg = blockIdx.x;
    const int dir = wg >> 6;
    const int wgu = wg & 63;
    const u16* __restrict__ zx = dir ? zxB : zxF;
    const u16* __restrict__ Ut = dir ? UtB : UtF;
    u16* __restrict__ hbuf = dir ? hbufB : hbufF;
    u32* __restrict__ ctr = dir ? ctrB : ctrF;

    const int tid = threadIdx.x;
    const int lane = tid & 63, w = tid >> 6;
    const int l15 = lane & 15, quad = lane >> 4;
    const bool hi = (lane & 8) != 0;
    // gate-col for this lane within N-tile nt: gcol = nt*1024 + gc_l
    const int gc_l = (l15 >> 3) * 512 + wgu * 8 + (l15 & 7);
    const int u = wgu * 8 + (lane & 7);
    const int brow = w * 16 + l15;  // batch row for A-operand

    // Preload U fragments into registers: 2 N-tiles x 16 K-chunks
    bf16x8 bfr[2][16];
#pragma unroll
    for (int nt = 0; nt < 2; ++nt)
#pragma unroll
        for (int kt = 0; kt < 16; ++kt)
            bfr[nt][kt] = *(const bf16x8*)&Ut[(size_t)(nt * 1024 + gc_l) * 512 + kt * 32 + quad * 8];

    float hreg[4] = {0.f, 0.f, 0.f, 0.f};
    float creg[4] = {0.f, 0.f, 0.f, 0.f};

    for (int s = 0; s < 256; ++s) {
        const int t = dir ? (255 - s) : s;
        const u16* __restrict__ zr = zx + (size_t)t * 64 * 2048;
        f32x4 acc0, acc1;
#pragma unroll
        for (int r = 0; r < 4; ++r) {
            int b = w * 16 + quad * 4 + r;
            acc0[r] = b2f(zr[b * 2048 + gc_l]);
            acc1[r] = b2f(zr[b * 2048 + 1024 + gc_l]);
        }
        const u16* __restrict__ hc = hbuf + (s & 1) * 32768;
#pragma unroll
        for (int kt = 0; kt < 16; ++kt) {
            bf16x8 a = *(const bf16x8*)&hc[brow * 512 + kt * 32 + quad * 8];
            acc0 = MFMA16(a, bfr[0][kt], acc0);
            acc1 = MFMA16(a, bfr[1][kt], acc1);
        }
        const u64 mw = maskw[t];
        u16* __restrict__ hn = hbuf + ((s + 1) & 1) * 32768;
#pragma unroll
        for (int r = 0; r < 4; ++r) {
            int b = w * 16 + quad * 4 + r;
            float z0 = acc0[r], z1 = acc1[r];
            float p0 = __shfl_xor(z0, 8);
            float p1 = __shfl_xor(z1, 8);
            float iz = hi ? p0 : z0, fz = hi ? z0 : p0;
            float gz = hi ? p1 : z1, oz = hi ? z1 : p1;
            float i_ = sigm(iz), f_ = sigm(fz), g_ = tanh_fast(gz), o_ = sigm(oz);
            float cn = f_ * creg[r] + i_ * g_;
            float hv = o_ * tanh_fast(cn);
            if (!((mw >> b) & 1ull)) { cn = creg[r]; hv = hreg[r]; }
            creg[r] = cn; hreg[r] = hv;
            if (!hi) {
                u16 hb = f2b(hv);
                hn[b * 512 + u] = hb;
                if (layer == 1)
                    out1[((size_t)t * 64 + b) * 1024 + dir * 512 + u] = hb;
                else
                    out2[(size_t)b * 262144 + (size_t)t * 1024 + dir * 512 + u] = hv;
            }
        }
        if (layer == 2 && s == 255 && !hi) {
#pragma unroll
            for (int r = 0; r < 4; ++r) {
                int b = w * 16 + quad * 4 + r;
                out2[16777216 + b * 1024 + dir * 512 + u] = hreg[r];
                out2[16777216 + 65536 + b * 1024 + dir * 512 + u] = creg[r];
            }
        }
        // release h stores, arrive, wait for all 64 WGs of this direction
        __threadfence();
        __syncthreads();
        if (tid == 0) {
            __hip_atomic_fetch_add(ctr, 1u, __ATOMIC_RELEASE, __HIP_MEMORY_SCOPE_AGENT);
            u32 tgt = 64u * (u32)(s + 1);
            while (__hip_atomic_load(ctr, __ATOMIC_ACQUIRE, __HIP_MEMORY_SCOPE_AGENT) < tgt)
                __builtin_amdgcn_s_sleep(2);
        }
        __syncthreads();
        __threadfence();
    }
}

// ---------------------------------------------------------------------------
extern "C" void kernel_launch(void* const* d_in, const int* in_sizes, int n_in,
                              void* d_out, int out_size, void* d_ws, size_t ws_size,
                              hipStream_t stream) {
    const int* enc = (const int*)d_in[0];
    const float* emb = (const float*)d_in[1];
    const float* W1f = (const float*)d_in[2];
    const float* U1f = (const float*)d_in[3];
    const float* b1f = (const float*)d_in[4];
    const float* W1b = (const float*)d_in[5];
    const float* U1b = (const float*)d_in[6];
    const float* b1b = (const float*)d_in[7];
    const float* W2f = (const float*)d_in[8];
    const float* U2f = (const float*)d_in[9];
    const float* b2f = (const float*)d_in[10];
    const float* W2b = (const float*)d_in[11];
    const float* U2b = (const float*)d_in[12];
    const float* b2b = (const float*)d_in[13];

    char* ws = (char*)d_ws;
    // ws layout (bytes)
    constexpr size_t ZXF = 0;                      // 67,108,864  bf16 [16384][2048]
    constexpr size_t ZXB = 67108864;               // 67,108,864
    constexpr size_t XB = 134217728;               // 16,777,216  bf16 [16384][512]
    constexpr size_t OUT1 = 150994944;             // 33,554,432  bf16 [16384][1024]
    constexpr size_t WT = 184549376;               // 20,971,520 packed bf16 transposed weights
    constexpr size_t W1FT = WT + 0;
    constexpr size_t W1BT = WT + 2097152;
    constexpr size_t U1FT = WT + 4194304;
    constexpr size_t U1BT = WT + 6291456;
    constexpr size_t W2FT = WT + 8388608;
    constexpr size_t W2BT = WT + 12582912;
    constexpr size_t U2FT = WT + 16777216;
    constexpr size_t U2BT = WT + 18874368;
    constexpr size_t HBUF = 205520896;             // 524,288: [layer][dir][2][64*512] bf16
    constexpr size_t CTR = HBUF + 524288;          // 16 bytes (4 counters)
    constexpr size_t MASKW = CTR + 64;             // 2048 bytes

    u16* zxF = (u16*)(ws + ZXF);
    u16* zxB = (u16*)(ws + ZXB);
    u16* xb = (u16*)(ws + XB);
    u16* out1 = (u16*)(ws + OUT1);
    u32* ctrs = (u32*)(ws + CTR);
    u64* maskw = (u64*)(ws + MASKW);

    // zero h init buffers + barrier counters (ws is poisoned 0xAA each launch)
    hipMemsetAsync(ws + HBUF, 0, 524288 + 64, stream);

    embed_k<<<8192, 256, 0, stream>>>(enc, emb, xb);
    mask_k<<<1, 256, 0, stream>>>(enc, maskw);

    castT_k<<<dim3(32, 8), 256, 0, stream>>>(W1f, (u16*)(ws + W1FT), 512, 2048);
    castT_k<<<dim3(32, 8), 256, 0, stream>>>(W1b, (u16*)(ws + W1BT), 512, 2048);
    castT_k<<<dim3(32, 8), 256, 0, stream>>>(U1f, (u16*)(ws + U1FT), 512, 2048);
    castT_k<<<dim3(32, 8), 256, 0, stream>>>(U1b, (u16*)(ws + U1BT), 512, 2048);
    castT_k<<<dim3(32, 16), 256, 0, stream>>>(W2f, (u16*)(ws + W2FT), 1024, 2048);
    castT_k<<<dim3(32, 16), 256, 0, stream>>>(W2b, (u16*)(ws + W2BT), 1024, 2048);
    castT_k<<<dim3(32, 8), 256, 0, stream>>>(U2f, (u16*)(ws + U2FT), 512, 2048);
    castT_k<<<dim3(32, 8), 256, 0, stream>>>(U2b, (u16*)(ws + U2BT), 512, 2048);

    // Layer 1: input projections + recurrence
    gemm_bias_k<<<dim3(16, 128, 2), 256, 0, stream>>>(
        xb, 512, (u16*)(ws + W1FT), (u16*)(ws + W1BT), b1f, b1b, zxF, zxB);
    lstm_rec_k<<<128, 256, 0, stream>>>(
        zxF, zxB, (u16*)(ws + U1FT), (u16*)(ws + U1BT), maskw,
        (u16*)(ws + HBUF), (u16*)(ws + HBUF + 131072),
        &ctrs[0], &ctrs[1], out1, nullptr, 1);

    // Layer 2: input projections + recurrence (writes d_out directly)
    gemm_bias_k<<<dim3(16, 128, 2), 256, 0, stream>>>(
        out1, 1024, (u16*)(ws + W2FT), (u16*)(ws + W2BT), b2f, b2b, zxF, zxB);
    lstm_rec_k<<<128, 256, 0, stream>>>(
        zxF, zxB, (u16*)(ws + U2FT), (u16*)(ws + U2BT), maskw,
        (u16*)(ws + HBUF + 262144), (u16*)(ws + HBUF + 393216),
        &ctrs[2], &ctrs[3], nullptr, (float*)d_out, 2);
}

// Round 4
// 5811.351 us; speedup vs baseline: 2.6835x; 2.6835x over previous
//
#include <hip/hip_runtime.h>

typedef unsigned short u16;
typedef unsigned int u32;
typedef unsigned long long u64;
typedef __attribute__((ext_vector_type(8))) short bf16x8;
typedef __attribute__((ext_vector_type(4))) float f32x4;
typedef __attribute__((ext_vector_type(8))) unsigned short u16x8;
typedef __attribute__((ext_vector_type(4))) unsigned short u16x4;

#define MFMA16(a, b, c) __builtin_amdgcn_mfma_f32_16x16x32_bf16(a, b, c, 0, 0, 0)

__device__ __forceinline__ u16 f2b(float f) {
    u32 u = __builtin_bit_cast(u32, f);
    u32 r = (u + 0x7fffu + ((u >> 16) & 1u)) >> 16;
    return (u16)r;
}
__device__ __forceinline__ float b2f(u16 h) {
    u32 u = ((u32)h) << 16;
    return __builtin_bit_cast(float, u);
}
__device__ __forceinline__ float sigm(float x) { return 1.0f / (1.0f + __expf(-x)); }
__device__ __forceinline__ float tanh_fast(float x) { return 1.0f - 2.0f / (__expf(2.0f * x) + 1.0f); }

// Cross-XCD-coherent accesses WITHOUT fences: agent-scope relaxed atomics
// lower to sc1 (MALL-coherent) global accesses. Compiler owns registers and
// waitcnt insertion -- no inline asm (rounds 2/3 failed on asm reg hazards).
__device__ __forceinline__ u64 aload64(const void* p) {
    return __hip_atomic_load((const u64*)p, __ATOMIC_RELAXED, __HIP_MEMORY_SCOPE_AGENT);
}
__device__ __forceinline__ void astore32(void* p, u32 v) {
    __hip_atomic_store((u32*)p, v, __ATOMIC_RELAXED, __HIP_MEMORY_SCOPE_AGENT);
}

// ---------------------------------------------------------------------------
// Embedding gather + f32->bf16 cast, time-major output x[t*64+b][e]
__global__ __launch_bounds__(256) void embed_k(const int* __restrict__ enc,
                                               const float* __restrict__ emb,
                                               u16* __restrict__ xb) {
    int idx = (blockIdx.x * 256 + threadIdx.x) * 4;
    int row = idx >> 9;
    int e = idx & 511;
    int t = row >> 6, b = row & 63;
    int tok = enc[b * 256 + t];
    const float4 v = *(const float4*)(emb + (size_t)tok * 512 + e);
    u16x4 o;
    o.x = f2b(v.x); o.y = f2b(v.y); o.z = f2b(v.z); o.w = f2b(v.w);
    *(u16x4*)(xb + idx) = o;
}

// Mask words: maskw[t] bit b = (enc[b][t] != 0)
__global__ void mask_k(const int* __restrict__ enc, u64* __restrict__ mw) {
    int t = threadIdx.x;
    u64 m = 0;
#pragma unroll 8
    for (int b = 0; b < 64; ++b)
        if (enc[b * 256 + t] != 0) m |= (1ull << b);
    mw[t] = m;
}

// ---------------------------------------------------------------------------
// Cast f32 [K][N] -> bf16 transposed [N][K] via LDS tile
__global__ __launch_bounds__(256) void castT_k(const float* __restrict__ src,
                                               u16* __restrict__ dst, int K, int N) {
    __shared__ float tile[64][65];
    int n0 = blockIdx.x * 64, k0 = blockIdx.y * 64;
    int tid = threadIdx.x;
#pragma unroll
    for (int it = 0; it < 4; ++it) {
        int e = tid + it * 256;
        int kk = e >> 4;
        int nn = (e & 15) * 4;
        const float4 v = *(const float4*)(src + (size_t)(k0 + kk) * N + n0 + nn);
        tile[kk][nn] = v.x; tile[kk][nn + 1] = v.y;
        tile[kk][nn + 2] = v.z; tile[kk][nn + 3] = v.w;
    }
    __syncthreads();
#pragma unroll
    for (int it = 0; it < 2; ++it) {
        int e = tid + it * 256;
        int nn = e >> 3;
        int ks = (e & 7) * 8;
        u16x8 o;
#pragma unroll
        for (int j = 0; j < 8; ++j) o[j] = f2b(tile[ks + j][nn]);
        *(u16x8*)(dst + (size_t)(n0 + nn) * K + k0 + ks) = o;
    }
}

// ---------------------------------------------------------------------------
// bf16 MFMA GEMM: zxT[dir][t][col][b] = (A[16384][Ak] @ Bt[dir]^T + bias[dir]),
// output TRANSPOSED per timestep for the recurrence's vectorized reads.
__global__ __launch_bounds__(256) void gemm_bias_k(
    const u16* __restrict__ A, int Ak,
    const u16* __restrict__ BtF, const u16* __restrict__ BtB,
    const float* __restrict__ biasF, const float* __restrict__ biasB,
    u16* __restrict__ outF, u16* __restrict__ outB) {
    const int dir = blockIdx.z;
    const u16* __restrict__ Bt = dir ? BtB : BtF;
    const float* __restrict__ bias = dir ? biasB : biasF;
    u16* __restrict__ out = dir ? outB : outF;

    const int m0 = blockIdx.y * 128, n0 = blockIdx.x * 128;
    __shared__ __align__(16) u16 As[128 * 40];
    __shared__ __align__(16) u16 Bs[128 * 40];
    const int tid = threadIdx.x;
    const int lane = tid & 63, w = tid >> 6;
    const int l15 = lane & 15, quad = lane >> 4;
    const int rb = (w >> 1) * 64, cb = (w & 1) * 64;

    f32x4 acc[4][4];
#pragma unroll
    for (int i = 0; i < 4; ++i)
#pragma unroll
        for (int j = 0; j < 4; ++j) acc[i][j] = (f32x4){0.f, 0.f, 0.f, 0.f};

    const int nkt = Ak >> 5;
    for (int kt = 0; kt < nkt; ++kt) {
        __syncthreads();
#pragma unroll
        for (int it = 0; it < 2; ++it) {
            int s = tid + it * 256;
            int r = s >> 2, seg = s & 3;
            *(uint4*)&As[r * 40 + seg * 8] =
                *(const uint4*)&A[(size_t)(m0 + r) * Ak + kt * 32 + seg * 8];
            *(uint4*)&Bs[r * 40 + seg * 8] =
                *(const uint4*)&Bt[(size_t)(n0 + r) * Ak + kt * 32 + seg * 8];
        }
        __syncthreads();
        bf16x8 af[4], bfr[4];
#pragma unroll
        for (int i = 0; i < 4; ++i)
            af[i] = *(const bf16x8*)&As[(rb + i * 16 + l15) * 40 + quad * 8];
#pragma unroll
        for (int j = 0; j < 4; ++j)
            bfr[j] = *(const bf16x8*)&Bs[(cb + j * 16 + l15) * 40 + quad * 8];
#pragma unroll
        for (int i = 0; i < 4; ++i)
#pragma unroll
            for (int j = 0; j < 4; ++j) acc[i][j] = MFMA16(af[i], bfr[j], acc[i][j]);
    }
    // epilogue: add bias, store bf16 transposed: zxT[(t*2048 + col)*64 + b]
    // rows m..m+3 share t because m === 0 (mod 4) and 64 | t-boundary.
#pragma unroll
    for (int j = 0; j < 4; ++j) {
        int col = n0 + cb + j * 16 + l15;
        float bv = bias[col];
#pragma unroll
        for (int i = 0; i < 4; ++i) {
            int m = m0 + rb + i * 16 + quad * 4;
            int t = m >> 6, b0 = m & 63;
            u16x4 o;
#pragma unroll
            for (int r = 0; r < 4; ++r) o[r] = f2b(acc[i][j][r] + bv);
            *(u16x4*)&out[((size_t)t * 2048 + col) * 64 + b0] = o;
        }
    }
}

// ---------------------------------------------------------------------------
// Persistent bidirectional LSTM recurrence, fence-free.
// 128 WGs: 0..63 fwd, 64..127 bwd. Each WG owns 8 units (32 gate-cols) with
// U-slices resident in registers. h exchange via agent-scope relaxed atomics
// (sc1 -> MALL, coherent across XCDs); producer arrive is a RELEASE add;
// zx[t+1] prefetched into registers while tid0 spins.
__global__ __launch_bounds__(256, 1) void lstm_rec_k(
    const u16* __restrict__ zxF, const u16* __restrict__ zxB,  // [256][2048][64]
    const u16* __restrict__ UtF, const u16* __restrict__ UtB,  // [2048][512]
    const u64* __restrict__ maskw,
    u16* __restrict__ hbufF, u16* __restrict__ hbufB,          // each 2*[64*512]
    u32* __restrict__ ctrF, u32* __restrict__ ctrB,
    u16* __restrict__ out1,    // layer 1: [256][64][1024] bf16
    float* __restrict__ out2,  // layer 2: d_out
    int layer) {
    const int wg = blockIdx.x;
    const int dir = wg >> 6;
    const int wgu = wg & 63;
    const u16* __restrict__ zx = dir ? zxB : zxF;
    const u16* __restrict__ Ut = dir ? UtB : UtF;
    u16* __restrict__ hbuf = dir ? hbufB : hbufF;
    u32* __restrict__ ctr = dir ? ctrB : ctrF;

    const int tid = threadIdx.x;
    const int lane = tid & 63, w = tid >> 6;
    const int l15 = lane & 15, quad = lane >> 4;
    const bool hi = (lane & 8) != 0;
    const int gc_l = (l15 >> 3) * 512 + wgu * 8 + (l15 & 7);
    const int u = wgu * 8 + (lane & 7);
    const int brow = w * 16 + l15;
    const int b0 = w * 16 + quad * 4;  // batch base for acc rows

    // Preload U fragments: 2 N-tiles x 16 K-chunks (VGPR/AGPR-resident)
    bf16x8 bfr[2][16];
#pragma unroll
    for (int nt = 0; nt < 2; ++nt)
#pragma unroll
        for (int kt = 0; kt < 16; ++kt)
            bfr[nt][kt] = *(const bf16x8*)&Ut[(size_t)(nt * 1024 + gc_l) * 512 + kt * 32 + quad * 8];

    float hreg[4] = {0.f, 0.f, 0.f, 0.f};
    float creg[4] = {0.f, 0.f, 0.f, 0.f};

    // initial zx prefetch (t of step 0)
    int t0 = dir ? 255 : 0;
    u16x4 pz0 = *(const u16x4*)&zx[((size_t)t0 * 2048 + gc_l) * 64 + b0];
    u16x4 pz1 = *(const u16x4*)&zx[((size_t)t0 * 2048 + 1024 + gc_l) * 64 + b0];

    union HU { u64 q[2]; bf16x8 v; };

    for (int s = 0; s < 256; ++s) {
        const int t = dir ? (255 - s) : s;
        // h[s] published by previous barrier (or memset for s=0): sc1 loads
        const u16* hbase = hbuf + (s & 1) * 32768 + brow * 512 + quad * 8;
        bf16x8 hfr[16];
#pragma unroll
        for (int kt = 0; kt < 16; ++kt) {
            HU hu;
            hu.q[0] = aload64(hbase + kt * 32);
            hu.q[1] = aload64(hbase + kt * 32 + 4);
            hfr[kt] = hu.v;
        }

        f32x4 acc0, acc1;
#pragma unroll
        for (int r = 0; r < 4; ++r) { acc0[r] = b2f(pz0[r]); acc1[r] = b2f(pz1[r]); }
#pragma unroll
        for (int kt = 0; kt < 16; ++kt) {
            acc0 = MFMA16(hfr[kt], bfr[0][kt], acc0);
            acc1 = MFMA16(hfr[kt], bfr[1][kt], acc1);
        }

        const u64 mw = maskw[t];
        u16* __restrict__ hn = hbuf + ((s + 1) & 1) * 32768;
#pragma unroll
        for (int r = 0; r < 4; ++r) {
            int b = b0 + r;
            float z0 = acc0[r], z1 = acc1[r];
            float p0 = __shfl_xor(z0, 8);
            float p1 = __shfl_xor(z1, 8);
            float iz = hi ? p0 : z0, fz = hi ? z0 : p0;
            float gz = hi ? p1 : z1, oz = hi ? z1 : p1;
            float i_ = sigm(iz), f_ = sigm(fz), g_ = tanh_fast(gz), o_ = sigm(oz);
            float cn = f_ * creg[r] + i_ * g_;
            float hv = o_ * tanh_fast(cn);
            if (!((mw >> b) & 1ull)) { cn = creg[r]; hv = hreg[r]; }
            creg[r] = cn; hreg[r] = hv;
            if (!hi) {
                u16 hb = f2b(hv);
                // pack (u, u+1) into u32; even lane stores (u is even there)
                u32 pair = (u32)hb | (((u32)(u16)__shfl_xor((int)(u32)hb, 1)) << 16);
                if (!(lane & 1)) {
                    astore32(&hn[b * 512 + u], pair);
                    if (layer == 1)
                        astore32(&out1[((size_t)t * 64 + b) * 1024 + dir * 512 + u], pair);
                }
                if (layer == 2)
                    astore32(&out2[(size_t)b * 262144 + (size_t)t * 1024 + dir * 512 + u],
                             __builtin_bit_cast(u32, hv));
            }
        }
        if (layer == 2 && s == 255 && !hi) {
#pragma unroll
            for (int r = 0; r < 4; ++r) {
                int b = b0 + r;
                astore32(&out2[16777216 + b * 1024 + dir * 512 + u],
                         __builtin_bit_cast(u32, hreg[r]));
                astore32(&out2[16777216 + 65536 + b * 1024 + dir * 512 + u],
                         __builtin_bit_cast(u32, creg[r]));
            }
        }

        // __syncthreads drains each wave's stores (compiler emits vmcnt(0)
        // before s_barrier); RELEASE add then publishes to agent scope.
        __syncthreads();
        if (tid == 0)
            __hip_atomic_fetch_add(ctr, 1u, __ATOMIC_RELEASE, __HIP_MEMORY_SCOPE_AGENT);
        // prefetch next step's zx into registers while tid0 spins
        {
            int tn = dir ? (s < 255 ? 254 - s : 0) : (s < 255 ? s + 1 : 255);
            pz0 = *(const u16x4*)&zx[((size_t)tn * 2048 + gc_l) * 64 + b0];
            pz1 = *(const u16x4*)&zx[((size_t)tn * 2048 + 1024 + gc_l) * 64 + b0];
        }
        if (tid == 0) {
            u32 tgt = 64u * (u32)(s + 1);
            while (__hip_atomic_load(ctr, __ATOMIC_RELAXED, __HIP_MEMORY_SCOPE_AGENT) < tgt)
                __builtin_amdgcn_s_sleep(1);
        }
        __syncthreads();
    }
}

// ---------------------------------------------------------------------------
extern "C" void kernel_launch(void* const* d_in, const int* in_sizes, int n_in,
                              void* d_out, int out_size, void* d_ws, size_t ws_size,
                              hipStream_t stream) {
    const int* enc = (const int*)d_in[0];
    const float* emb = (const float*)d_in[1];
    const float* W1f = (const float*)d_in[2];
    const float* U1f = (const float*)d_in[3];
    const float* b1f = (const float*)d_in[4];
    const float* W1b = (const float*)d_in[5];
    const float* U1b = (const float*)d_in[6];
    const float* b1b = (const float*)d_in[7];
    const float* W2f = (const float*)d_in[8];
    const float* U2f = (const float*)d_in[9];
    const float* b2f = (const float*)d_in[10];
    const float* W2b = (const float*)d_in[11];
    const float* U2b = (const float*)d_in[12];
    const float* b2b = (const float*)d_in[13];

    char* ws = (char*)d_ws;
    constexpr size_t ZXF = 0;                      // 67,108,864  bf16 [256][2048][64]
    constexpr size_t ZXB = 67108864;               // 67,108,864
    constexpr size_t XB = 134217728;               // 16,777,216  bf16 [16384][512]
    constexpr size_t OUT1 = 150994944;             // 33,554,432  bf16 [16384][1024]
    constexpr size_t WT = 184549376;               // 20,971,520 packed bf16 transposed weights
    constexpr size_t W1FT = WT + 0;
    constexpr size_t W1BT = WT + 2097152;
    constexpr size_t U1FT = WT + 4194304;
    constexpr size_t U1BT = WT + 6291456;
    constexpr size_t W2FT = WT + 8388608;
    constexpr size_t W2BT = WT + 12582912;
    constexpr size_t U2FT = WT + 16777216;
    constexpr size_t U2BT = WT + 18874368;
    constexpr size_t HBUF = 205520896;             // 524,288: [layer][dir][2][64*512] bf16
    constexpr size_t CTR = HBUF + 524288;          // 4 counters
    constexpr size_t MASKW = CTR + 64;             // 2048 bytes

    u16* zxF = (u16*)(ws + ZXF);
    u16* zxB = (u16*)(ws + ZXB);
    u16* xb = (u16*)(ws + XB);
    u16* out1 = (u16*)(ws + OUT1);
    u32* ctrs = (u32*)(ws + CTR);
    u64* maskw = (u64*)(ws + MASKW);

    hipMemsetAsync(ws + HBUF, 0, 524288 + 64, stream);

    embed_k<<<8192, 256, 0, stream>>>(enc, emb, xb);
    mask_k<<<1, 256, 0, stream>>>(enc, maskw);

    castT_k<<<dim3(32, 8), 256, 0, stream>>>(W1f, (u16*)(ws + W1FT), 512, 2048);
    castT_k<<<dim3(32, 8), 256, 0, stream>>>(W1b, (u16*)(ws + W1BT), 512, 2048);
    castT_k<<<dim3(32, 8), 256, 0, stream>>>(U1f, (u16*)(ws + U1FT), 512, 2048);
    castT_k<<<dim3(32, 8), 256, 0, stream>>>(U1b, (u16*)(ws + U1BT), 512, 2048);
    castT_k<<<dim3(32, 16), 256, 0, stream>>>(W2f, (u16*)(ws + W2FT), 1024, 2048);
    castT_k<<<dim3(32, 16), 256, 0, stream>>>(W2b, (u16*)(ws + W2BT), 1024, 2048);
    castT_k<<<dim3(32, 8), 256, 0, stream>>>(U2f, (u16*)(ws + U2FT), 512, 2048);
    castT_k<<<dim3(32, 8), 256, 0, stream>>>(U2b, (u16*)(ws + U2BT), 512, 2048);

    gemm_bias_k<<<dim3(16, 128, 2), 256, 0, stream>>>(
        xb, 512, (u16*)(ws + W1FT), (u16*)(ws + W1BT), b1f, b1b, zxF, zxB);
    lstm_rec_k<<<128, 256, 0, stream>>>(
        zxF, zxB, (u16*)(ws + U1FT), (u16*)(ws + U1BT), maskw,
        (u16*)(ws + HBUF), (u16*)(ws + HBUF + 131072),
        &ctrs[0], &ctrs[1], out1, nullptr, 1);

    gemm_bias_k<<<dim3(16, 128, 2), 256, 0, stream>>>(
        out1, 1024, (u16*)(ws + W2FT), (u16*)(ws + W2BT), b2f, b2b, zxF, zxB);
    lstm_rec_k<<<128, 256, 0, stream>>>(
        zxF, zxB, (u16*)(ws + U2FT), (u16*)(ws + U2BT), maskw,
        (u16*)(ws + HBUF + 262144), (u16*)(ws + HBUF + 393216),
        &ctrs[2], &ctrs[3], nullptr, (float*)d_out, 2);
}

// Round 5
// 3580.727 us; speedup vs baseline: 4.3552x; 1.6230x over previous
//
#include <hip/hip_runtime.h>

typedef unsigned short u16;
typedef unsigned int u32;
typedef unsigned long long u64;
typedef __attribute__((ext_vector_type(8))) short bf16x8;
typedef __attribute__((ext_vector_type(4))) float f32x4;
typedef __attribute__((ext_vector_type(8))) unsigned short u16x8;
typedef __attribute__((ext_vector_type(4))) unsigned short u16x4;

#define MFMA16(a, b, c) __builtin_amdgcn_mfma_f32_16x16x32_bf16(a, b, c, 0, 0, 0)

__device__ __forceinline__ u16 f2b(float f) {
    u32 u = __builtin_bit_cast(u32, f);
    u32 r = (u + 0x7fffu + ((u >> 16) & 1u)) >> 16;
    return (u16)r;
}
__device__ __forceinline__ float b2f(u16 h) {
    u32 u = ((u32)h) << 16;
    return __builtin_bit_cast(float, u);
}
__device__ __forceinline__ float sigm(float x) { return 1.0f / (1.0f + __expf(-x)); }
__device__ __forceinline__ float tanh_fast(float x) { return 1.0f - 2.0f / (__expf(2.0f * x) + 1.0f); }

// Cross-XCD-coherent accesses WITHOUT fences: agent-scope relaxed atomics
// lower to sc1 (MALL-coherent) global accesses. Compiler owns registers and
// waitcnt insertion -- no inline asm (rounds 2/3 failed on asm reg hazards).
// No release/acquire anywhere: sc1 stores complete at the MALL before the
// pre-barrier vmcnt(0) drain, so a later relaxed flag store is observed
// strictly after them. Avoids buffer_wbl2/buffer_inv entirely.
__device__ __forceinline__ u64 aload64(const void* p) {
    return __hip_atomic_load((const u64*)p, __ATOMIC_RELAXED, __HIP_MEMORY_SCOPE_AGENT);
}
__device__ __forceinline__ u32 aload32(const void* p) {
    return __hip_atomic_load((const u32*)p, __ATOMIC_RELAXED, __HIP_MEMORY_SCOPE_AGENT);
}
__device__ __forceinline__ void astore32(void* p, u32 v) {
    __hip_atomic_store((u32*)p, v, __ATOMIC_RELAXED, __HIP_MEMORY_SCOPE_AGENT);
}

// ---------------------------------------------------------------------------
// Embedding gather + f32->bf16 cast, time-major output x[t*64+b][e]
__global__ __launch_bounds__(256) void embed_k(const int* __restrict__ enc,
                                               const float* __restrict__ emb,
                                               u16* __restrict__ xb) {
    int idx = (blockIdx.x * 256 + threadIdx.x) * 4;
    int row = idx >> 9;
    int e = idx & 511;
    int t = row >> 6, b = row & 63;
    int tok = enc[b * 256 + t];
    const float4 v = *(const float4*)(emb + (size_t)tok * 512 + e);
    u16x4 o;
    o.x = f2b(v.x); o.y = f2b(v.y); o.z = f2b(v.z); o.w = f2b(v.w);
    *(u16x4*)(xb + idx) = o;
}

// Mask words: maskw[t] bit b = (enc[b][t] != 0)
__global__ void mask_k(const int* __restrict__ enc, u64* __restrict__ mw) {
    int t = threadIdx.x;
    u64 m = 0;
#pragma unroll 8
    for (int b = 0; b < 64; ++b)
        if (enc[b * 256 + t] != 0) m |= (1ull << b);
    mw[t] = m;
}

// ---------------------------------------------------------------------------
// Cast f32 [K][N] -> bf16 transposed [N][K] via LDS tile
__global__ __launch_bounds__(256) void castT_k(const float* __restrict__ src,
                                               u16* __restrict__ dst, int K, int N) {
    __shared__ float tile[64][65];
    int n0 = blockIdx.x * 64, k0 = blockIdx.y * 64;
    int tid = threadIdx.x;
#pragma unroll
    for (int it = 0; it < 4; ++it) {
        int e = tid + it * 256;
        int kk = e >> 4;
        int nn = (e & 15) * 4;
        const float4 v = *(const float4*)(src + (size_t)(k0 + kk) * N + n0 + nn);
        tile[kk][nn] = v.x; tile[kk][nn + 1] = v.y;
        tile[kk][nn + 2] = v.z; tile[kk][nn + 3] = v.w;
    }
    __syncthreads();
#pragma unroll
    for (int it = 0; it < 2; ++it) {
        int e = tid + it * 256;
        int nn = e >> 3;
        int ks = (e & 7) * 8;
        u16x8 o;
#pragma unroll
        for (int j = 0; j < 8; ++j) o[j] = f2b(tile[ks + j][nn]);
        *(u16x8*)(dst + (size_t)(n0 + nn) * K + k0 + ks) = o;
    }
}

// ---------------------------------------------------------------------------
// bf16 MFMA GEMM: zxT[dir][t][col][b] = (A[16384][Ak] @ Bt[dir]^T + bias[dir]),
// output TRANSPOSED per timestep for the recurrence's vectorized reads.
__global__ __launch_bounds__(256) void gemm_bias_k(
    const u16* __restrict__ A, int Ak,
    const u16* __restrict__ BtF, const u16* __restrict__ BtB,
    const float* __restrict__ biasF, const float* __restrict__ biasB,
    u16* __restrict__ outF, u16* __restrict__ outB) {
    const int dir = blockIdx.z;
    const u16* __restrict__ Bt = dir ? BtB : BtF;
    const float* __restrict__ bias = dir ? biasB : biasF;
    u16* __restrict__ out = dir ? outB : outF;

    const int m0 = blockIdx.y * 128, n0 = blockIdx.x * 128;
    __shared__ __align__(16) u16 As[128 * 40];
    __shared__ __align__(16) u16 Bs[128 * 40];
    const int tid = threadIdx.x;
    const int lane = tid & 63, w = tid >> 6;
    const int l15 = lane & 15, quad = lane >> 4;
    const int rb = (w >> 1) * 64, cb = (w & 1) * 64;

    f32x4 acc[4][4];
#pragma unroll
    for (int i = 0; i < 4; ++i)
#pragma unroll
        for (int j = 0; j < 4; ++j) acc[i][j] = (f32x4){0.f, 0.f, 0.f, 0.f};

    const int nkt = Ak >> 5;
    for (int kt = 0; kt < nkt; ++kt) {
        __syncthreads();
#pragma unroll
        for (int it = 0; it < 2; ++it) {
            int s = tid + it * 256;
            int r = s >> 2, seg = s & 3;
            *(uint4*)&As[r * 40 + seg * 8] =
                *(const uint4*)&A[(size_t)(m0 + r) * Ak + kt * 32 + seg * 8];
            *(uint4*)&Bs[r * 40 + seg * 8] =
                *(const uint4*)&Bt[(size_t)(n0 + r) * Ak + kt * 32 + seg * 8];
        }
        __syncthreads();
        bf16x8 af[4], bfr[4];
#pragma unroll
        for (int i = 0; i < 4; ++i)
            af[i] = *(const bf16x8*)&As[(rb + i * 16 + l15) * 40 + quad * 8];
#pragma unroll
        for (int j = 0; j < 4; ++j)
            bfr[j] = *(const bf16x8*)&Bs[(cb + j * 16 + l15) * 40 + quad * 8];
#pragma unroll
        for (int i = 0; i < 4; ++i)
#pragma unroll
            for (int j = 0; j < 4; ++j) acc[i][j] = MFMA16(af[i], bfr[j], acc[i][j]);
    }
    // epilogue: add bias, store bf16 transposed: zxT[(t*2048 + col)*64 + b]
    // rows m..m+3 share t because m === 0 (mod 4) and 64 | t-boundary.
#pragma unroll
    for (int j = 0; j < 4; ++j) {
        int col = n0 + cb + j * 16 + l15;
        float bv = bias[col];
#pragma unroll
        for (int i = 0; i < 4; ++i) {
            int m = m0 + rb + i * 16 + quad * 4;
            int t = m >> 6, b0 = m & 63;
            u16x4 o;
#pragma unroll
            for (int r = 0; r < 4; ++r) o[r] = f2b(acc[i][j][r] + bv);
            *(u16x4*)&out[((size_t)t * 2048 + col) * 64 + b0] = o;
        }
    }
}

// ---------------------------------------------------------------------------
// Persistent bidirectional LSTM recurrence, fence-free.
// 128 WGs: 0..63 fwd, 64..127 bwd. Each WG owns 8 units (32 gate-cols) with
// U-slices resident in registers. h exchange via agent-scope relaxed atomics
// (sc1 -> MALL, coherent across XCDs).
// Barrier = per-WG FLAG ARRAY (single-writer relaxed store of step number) +
// wave-parallel poll (wave 0, lane i watches flag[i], ballot-until-all).
// No atomic RMW contention, no release -> no buffer_wbl2 in the loop.
__global__ __launch_bounds__(256, 1) void lstm_rec_k(
    const u16* __restrict__ zxF, const u16* __restrict__ zxB,  // [256][2048][64]
    const u16* __restrict__ UtF, const u16* __restrict__ UtB,  // [2048][512]
    const u64* __restrict__ maskw,
    u16* __restrict__ hbufF, u16* __restrict__ hbufB,          // each 2*[64*512]
    u32* __restrict__ flgF, u32* __restrict__ flgB,            // each [64]
    u16* __restrict__ out1,    // layer 1: [256][64][1024] bf16
    float* __restrict__ out2,  // layer 2: d_out
    int layer) {
    const int wg = blockIdx.x;
    const int dir = wg >> 6;
    const int wgu = wg & 63;
    const u16* __restrict__ zx = dir ? zxB : zxF;
    const u16* __restrict__ Ut = dir ? UtB : UtF;
    u16* __restrict__ hbuf = dir ? hbufB : hbufF;
    u32* __restrict__ flg = dir ? flgB : flgF;

    const int tid = threadIdx.x;
    const int lane = tid & 63, w = tid >> 6;
    const int l15 = lane & 15, quad = lane >> 4;
    const bool hi = (lane & 8) != 0;
    const int gc_l = (l15 >> 3) * 512 + wgu * 8 + (l15 & 7);
    const int u = wgu * 8 + (lane & 7);
    const int brow = w * 16 + l15;
    const int b0 = w * 16 + quad * 4;  // batch base for acc rows

    // Preload U fragments: 2 N-tiles x 16 K-chunks (VGPR/AGPR-resident)
    bf16x8 bfr[2][16];
#pragma unroll
    for (int nt = 0; nt < 2; ++nt)
#pragma unroll
        for (int kt = 0; kt < 16; ++kt)
            bfr[nt][kt] = *(const bf16x8*)&Ut[(size_t)(nt * 1024 + gc_l) * 512 + kt * 32 + quad * 8];

    float hreg[4] = {0.f, 0.f, 0.f, 0.f};
    float creg[4] = {0.f, 0.f, 0.f, 0.f};

    // initial zx prefetch (t of step 0)
    int t0 = dir ? 255 : 0;
    u16x4 pz0 = *(const u16x4*)&zx[((size_t)t0 * 2048 + gc_l) * 64 + b0];
    u16x4 pz1 = *(const u16x4*)&zx[((size_t)t0 * 2048 + 1024 + gc_l) * 64 + b0];

    union HU { u64 q[2]; bf16x8 v; };

    for (int s = 0; s < 256; ++s) {
        const int t = dir ? (255 - s) : s;

        // gate: wait until all 64 WGs of this direction published step s
        // (i.e. finished step s-1 including their h reads -> WAR-safe).
        if (s) {
            if (tid < 64) {
                u32 v = aload32(&flg[tid]);
                while (__ballot(v < (u32)s)) v = aload32(&flg[tid]);
            }
            __syncthreads();
        }

        // h[s] slot: sc1 loads from MALL
        const u16* hbase = hbuf + (s & 1) * 32768 + brow * 512 + quad * 8;
        bf16x8 hfr[16];
#pragma unroll
        for (int kt = 0; kt < 16; ++kt) {
            HU hu;
            hu.q[0] = aload64(hbase + kt * 32);
            hu.q[1] = aload64(hbase + kt * 32 + 4);
            hfr[kt] = hu.v;
        }

        f32x4 acc0, acc1;
#pragma unroll
        for (int r = 0; r < 4; ++r) { acc0[r] = b2f(pz0[r]); acc1[r] = b2f(pz1[r]); }
#pragma unroll
        for (int kt = 0; kt < 16; ++kt) {
            acc0 = MFMA16(hfr[kt], bfr[0][kt], acc0);
            acc1 = MFMA16(hfr[kt], bfr[1][kt], acc1);
        }

        const u64 mw = maskw[t];
        u16* __restrict__ hn = hbuf + ((s + 1) & 1) * 32768;
        u32 pairs[4];
#pragma unroll
        for (int r = 0; r < 4; ++r) {
            int b = b0 + r;
            float z0 = acc0[r], z1 = acc1[r];
            float p0 = __shfl_xor(z0, 8);
            float p1 = __shfl_xor(z1, 8);
            float iz = hi ? p0 : z0, fz = hi ? z0 : p0;
            float gz = hi ? p1 : z1, oz = hi ? z1 : p1;
            float i_ = sigm(iz), f_ = sigm(fz), g_ = tanh_fast(gz), o_ = sigm(oz);
            float cn = f_ * creg[r] + i_ * g_;
            float hv = o_ * tanh_fast(cn);
            if (!((mw >> b) & 1ull)) { cn = creg[r]; hv = hreg[r]; }
            creg[r] = cn; hreg[r] = hv;
            if (!hi) {
                u16 hb = f2b(hv);
                // pack (u, u+1) into u32; even lane stores (u is even there)
                u32 pair = (u32)hb | (((u32)(u16)__shfl_xor((int)(u32)hb, 1)) << 16);
                pairs[r] = pair;
                if (!(lane & 1)) astore32(&hn[b * 512 + u], pair);
            }
        }

        // drain hn stores (compiler emits vmcnt(0) before s_barrier), publish
        __syncthreads();
        if (tid == 0) astore32(&flg[wgu], (u32)(s + 1));

        // post-publish: out stores + next-step zx prefetch overlap the gate
        if (!hi) {
#pragma unroll
            for (int r = 0; r < 4; ++r) {
                int b = b0 + r;
                if (layer == 1) {
                    if (!(lane & 1))
                        astore32(&out1[((size_t)t * 64 + b) * 1024 + dir * 512 + u], pairs[r]);
                } else {
                    astore32(&out2[(size_t)b * 262144 + (size_t)t * 1024 + dir * 512 + u],
                             __builtin_bit_cast(u32, hreg[r]));
                }
            }
        }
        if (layer == 2 && s == 255 && !hi) {
#pragma unroll
            for (int r = 0; r < 4; ++r) {
                int b = b0 + r;
                astore32(&out2[16777216 + b * 1024 + dir * 512 + u],
                         __builtin_bit_cast(u32, hreg[r]));
                astore32(&out2[16777216 + 65536 + b * 1024 + dir * 512 + u],
                         __builtin_bit_cast(u32, creg[r]));
            }
        }
        {
            int tn = dir ? (s < 255 ? 254 - s : 0) : (s < 255 ? s + 1 : 255);
            pz0 = *(const u16x4*)&zx[((size_t)tn * 2048 + gc_l) * 64 + b0];
            pz1 = *(const u16x4*)&zx[((size_t)tn * 2048 + 1024 + gc_l) * 64 + b0];
        }
    }
}

// ---------------------------------------------------------------------------
extern "C" void kernel_launch(void* const* d_in, const int* in_sizes, int n_in,
                              void* d_out, int out_size, void* d_ws, size_t ws_size,
                              hipStream_t stream) {
    const int* enc = (const int*)d_in[0];
    const float* emb = (const float*)d_in[1];
    const float* W1f = (const float*)d_in[2];
    const float* U1f = (const float*)d_in[3];
    const float* b1f = (const float*)d_in[4];
    const float* W1b = (const float*)d_in[5];
    const float* U1b = (const float*)d_in[6];
    const float* b1b = (const float*)d_in[7];
    const float* W2f = (const float*)d_in[8];
    const float* U2f = (const float*)d_in[9];
    const float* b2f = (const float*)d_in[10];
    const float* W2b = (const float*)d_in[11];
    const float* U2b = (const float*)d_in[12];
    const float* b2b = (const float*)d_in[13];

    char* ws = (char*)d_ws;
    constexpr size_t ZXF = 0;                      // 67,108,864  bf16 [256][2048][64]
    constexpr size_t ZXB = 67108864;               // 67,108,864
    constexpr size_t XB = 134217728;               // 16,777,216  bf16 [16384][512]
    constexpr size_t OUT1 = 150994944;             // 33,554,432  bf16 [16384][1024]
    constexpr size_t WT = 184549376;               // 20,971,520 packed bf16 transposed weights
    constexpr size_t W1FT = WT + 0;
    constexpr size_t W1BT = WT + 2097152;
    constexpr size_t U1FT = WT + 4194304;
    constexpr size_t U1BT = WT + 6291456;
    constexpr size_t W2FT = WT + 8388608;
    constexpr size_t W2BT = WT + 12582912;
    constexpr size_t U2FT = WT + 16777216;
    constexpr size_t U2BT = WT + 18874368;
    constexpr size_t HBUF = 205520896;             // 524,288: [layer][dir][2][64*512] bf16
    constexpr size_t FLG = HBUF + 524288;          // 4 x 64 u32 = 1024 B
    constexpr size_t MASKW = FLG + 1024;           // 2048 bytes

    u16* zxF = (u16*)(ws + ZXF);
    u16* zxB = (u16*)(ws + ZXB);
    u16* xb = (u16*)(ws + XB);
    u16* out1 = (u16*)(ws + OUT1);
    u32* flgs = (u32*)(ws + FLG);
    u64* maskw = (u64*)(ws + MASKW);

    // zero h init buffers + flags (ws is poisoned 0xAA each launch)
    hipMemsetAsync(ws + HBUF, 0, 524288 + 1024, stream);

    embed_k<<<8192, 256, 0, stream>>>(enc, emb, xb);
    mask_k<<<1, 256, 0, stream>>>(enc, maskw);

    castT_k<<<dim3(32, 8), 256, 0, stream>>>(W1f, (u16*)(ws + W1FT), 512, 2048);
    castT_k<<<dim3(32, 8), 256, 0, stream>>>(W1b, (u16*)(ws + W1BT), 512, 2048);
    castT_k<<<dim3(32, 8), 256, 0, stream>>>(U1f, (u16*)(ws + U1FT), 512, 2048);
    castT_k<<<dim3(32, 8), 256, 0, stream>>>(U1b, (u16*)(ws + U1BT), 512, 2048);
    castT_k<<<dim3(32, 16), 256, 0, stream>>>(W2f, (u16*)(ws + W2FT), 1024, 2048);
    castT_k<<<dim3(32, 16), 256, 0, stream>>>(W2b, (u16*)(ws + W2BT), 1024, 2048);
    castT_k<<<dim3(32, 8), 256, 0, stream>>>(U2f, (u16*)(ws + U2FT), 512, 2048);
    castT_k<<<dim3(32, 8), 256, 0, stream>>>(U2b, (u16*)(ws + U2BT), 512, 2048);

    gemm_bias_k<<<dim3(16, 128, 2), 256, 0, stream>>>(
        xb, 512, (u16*)(ws + W1FT), (u16*)(ws + W1BT), b1f, b1b, zxF, zxB);
    lstm_rec_k<<<128, 256, 0, stream>>>(
        zxF, zxB, (u16*)(ws + U1FT), (u16*)(ws + U1BT), maskw,
        (u16*)(ws + HBUF), (u16*)(ws + HBUF + 131072),
        &flgs[0], &flgs[64], out1, nullptr, 1);

    gemm_bias_k<<<dim3(16, 128, 2), 256, 0, stream>>>(
        out1, 1024, (u16*)(ws + W2FT), (u16*)(ws + W2BT), b2f, b2b, zxF, zxB);
    lstm_rec_k<<<128, 256, 0, stream>>>(
        zxF, zxB, (u16*)(ws + U2FT), (u16*)(ws + U2BT), maskw,
        (u16*)(ws + HBUF + 262144), (u16*)(ws + HBUF + 393216),
        &flgs[128], &flgs[192], nullptr, (float*)d_out, 2);
}